// Round 7
// baseline (110.387 us; speedup 1.0000x reference)
//
#include <hip/hip_runtime.h>

// Batched 3x3 expm(T) @ x, T = sum_m c[b,m]*psi[m]. Scalar Cayley-Hamilton
// pipeline (R6): order-8 reduced Taylor + 2 squarings in coefficient space,
// tail y = b0 x + (b1/4)Tx + (b2/16)T(Tx). New in R7:
//  - psi in __constant__ (AS4): uniform-index reads are guaranteed s_load
//    (SGPR operands), zero per-thread VMEM for psi. Copied on every launch
//    via hipMemcpyToSymbolAsync (graph-capture safe d2d).
//  - TWO batches/thread (R4's 4-batch blew the 64-VGPR occupancy cliff;
//    2 fits): c = 3x dwordx4, x = 3x dwordx2, out = 3x dwordx2, all
//    exactly aligned. 9 VMEM per 2 batches vs 18.
__constant__ float g_psi[54];

__global__ __launch_bounds__(256) void expm_kernel(
    const float2* __restrict__ x2,
    const float4* __restrict__ c4,
    float2* __restrict__ o2)
{
    const int t = blockIdx.x * blockDim.x + threadIdx.x;  // Tn = B/2 exact

    // ---- vector loads: 2 batches = 12 c-floats (48B, 16-aligned),
    //      6 x-floats (24B, 8-aligned) ----
    const float4 cA = c4[(size_t)t * 3 + 0];
    const float4 cB = c4[(size_t)t * 3 + 1];
    const float4 cC = c4[(size_t)t * 3 + 2];
    const float2 xA = x2[(size_t)t * 3 + 0];
    const float2 xB = x2[(size_t)t * 3 + 1];
    const float2 xC = x2[(size_t)t * 3 + 2];

    const float cm[2][6] = {{cA.x, cA.y, cA.z, cA.w, cB.x, cB.y},
                            {cB.z, cB.w, cC.x, cC.y, cC.z, cC.w}};
    const float xs[2][3] = {{xA.x, xA.y, xB.x}, {xB.y, xC.x, xC.y}};
    float ys[2][3];

#pragma unroll
    for (int u = 0; u < 2; ++u) {
        // ---- T = sum_m c[m] * psi[m]  (psi: SGPR via constant AS) ----
        float T[9];
#pragma unroll
        for (int j = 0; j < 9; ++j) {
            float s = cm[u][0] * g_psi[0 * 9 + j];
#pragma unroll
            for (int m = 1; m < 6; ++m) s = fmaf(cm[u][m], g_psi[m * 9 + j], s);
            T[j] = s;
        }

        // ---- invariants of T, scaled to A = T/4:
        //      lam^3 = c2v lam^2 + c1v lam + c0v ----
        const float trT = T[0] + T[4] + T[8];
        const float m01 = fmaf(T[0], T[4], -T[1] * T[3]);
        const float m02 = fmaf(T[0], T[8], -T[2] * T[6]);
        const float m12 = fmaf(T[4], T[8], -T[5] * T[7]);
        const float msT = m01 + m02 + m12;
        const float M10 = fmaf(T[3], T[8], -T[5] * T[6]);
        const float M20 = fmaf(T[3], T[7], -T[4] * T[6]);
        const float detT = fmaf(T[0], m12, fmaf(-T[1], M10, T[2] * M20));
        const float c2v = trT * 0.25f;
        const float c1v = msT * -0.0625f;
        const float c0v = detT * 0.015625f;

        // lam^4 fold-back (shared by both squarings)
        const float d2 = fmaf(c2v, c2v, c1v);
        const float d1 = fmaf(c2v, c1v, c0v);
        const float d0 = c2v * c0v;

        // ---- order-8 reduced Taylor: exp(A) ~ b0 I + b1 A + b2 A^2 ----
        float p0 = 0.0f, p1 = 0.0f, p2 = 1.0f;
        float b0 = 1.0f, b1 = 1.0f, b2 = 0.5f;
        const float invfact[9] = {0, 0, 0,
            1.6666667e-1f, 4.1666667e-2f, 8.3333333e-3f,
            1.3888889e-3f, 1.9841270e-4f, 2.4801587e-5f};
#pragma unroll
        for (int k = 3; k <= 8; ++k) {
            const float t0 = c0v * p2;
            const float t1 = fmaf(c1v, p2, p0);
            const float t2 = fmaf(c2v, p2, p1);
            p0 = t0; p1 = t1; p2 = t2;
            const float f = invfact[k];  // constant after unroll
            b0 = fmaf(p0, f, b0);
            b1 = fmaf(p1, f, b1);
            b2 = fmaf(p2, f, b2);
        }

        // ---- two squarings in coefficient space ----
#pragma unroll
        for (int s2 = 0; s2 < 2; ++s2) {
            const float q0 = b0 * b0;
            const float q1 = 2.0f * (b0 * b1);
            const float q2 = fmaf(b1, b1, 2.0f * (b0 * b2));
            const float q3 = 2.0f * (b1 * b2);
            const float q4 = b2 * b2;
            b0 = fmaf(d0, q4, fmaf(c0v, q3, q0));
            b1 = fmaf(d1, q4, fmaf(c1v, q3, q1));
            b2 = fmaf(d2, q4, fmaf(c2v, q3, q2));
        }
        const float b1q = b1 * 0.25f;
        const float b2q = b2 * 0.0625f;

        // ---- y = b0 x + b1q (Tx) + b2q T(Tx) ----
        const float x0 = xs[u][0], x1 = xs[u][1], x2v = xs[u][2];
        const float w0 = fmaf(T[0], x0, fmaf(T[1], x1, T[2] * x2v));
        const float w1 = fmaf(T[3], x0, fmaf(T[4], x1, T[5] * x2v));
        const float w2 = fmaf(T[6], x0, fmaf(T[7], x1, T[8] * x2v));
        const float v0 = fmaf(T[0], w0, fmaf(T[1], w1, T[2] * w2));
        const float v1 = fmaf(T[3], w0, fmaf(T[4], w1, T[5] * w2));
        const float v2 = fmaf(T[6], w0, fmaf(T[7], w1, T[8] * w2));
        ys[u][0] = fmaf(b0, x0, fmaf(b1q, w0, b2q * v0));
        ys[u][1] = fmaf(b0, x1, fmaf(b1q, w1, b2q * v1));
        ys[u][2] = fmaf(b0, x2v, fmaf(b1q, w2, b2q * v2));
    }

    // ---- vector stores: 6 out-floats as 3x float2 ----
    float2 oA, oB, oC;
    oA.x = ys[0][0]; oA.y = ys[0][1];
    oB.x = ys[0][2]; oB.y = ys[1][0];
    oC.x = ys[1][1]; oC.y = ys[1][2];
    o2[(size_t)t * 3 + 0] = oA;
    o2[(size_t)t * 3 + 1] = oB;
    o2[(size_t)t * 3 + 2] = oC;
}

extern "C" void kernel_launch(void* const* d_in, const int* in_sizes, int n_in,
                              void* d_out, int out_size, void* d_ws, size_t ws_size,
                              hipStream_t stream) {
    const float2* x2 = (const float2*)d_in[0];  // [B,3,1]
    const float4* c4 = (const float4*)d_in[1];  // [B,6]
    float2* o2 = (float2*)d_out;                // [B,3,1]

    // psi -> __constant__ (d2d async copy; graph-capture safe, every call)
    hipMemcpyToSymbolAsync(HIP_SYMBOL(g_psi), d_in[2], 54 * sizeof(float), 0,
                           hipMemcpyDeviceToDevice, stream);

    const int B = in_sizes[1] / 6;  // 2097152 = 2^21
    const int Tn = B / 2;
    const int block = 256;
    const int grid = Tn / block;
    expm_kernel<<<grid, block, 0, stream>>>(x2, c4, o2);
}

// Round 8
// 103.546 us; speedup vs baseline: 1.0661x; 1.0661x over previous
//
#include <hip/hip_runtime.h>

// Batched 3x3 expm(T) @ x, T = sum_m c[b,m]*psi[m]. Scalar Cayley-Hamilton
// pipeline, one batch per thread (R4/R7: multi-batch crosses the 64-VGPR
// occupancy cliff and regresses; R5: LDS-coalesced I/O regresses).
//  (1) exp(A) = b0 I + b1 A + b2 A^2 (A = T/4) via HORNER IN THE QUOTIENT
//      RING: h <- h*lam + 1/k! with h=(b0,b1,b2) reduced mod char-poly on
//      the fly — 3 FMA/order (24 ops) vs power-basis recurrence (54 ops).
//  (2) two squarings in coefficient space (15 ops each; E never formed).
//  (3) tail y = b0 x + (b1/4) Tx + (b2/16) T(Tx).
// ~160 core ops/thread. psi reads are uniform-address -> compiler emits
// s_loads (verified pattern; __constant__ variant was neutral + extra
// dispatch).
__global__ __launch_bounds__(256) void expm_kernel(
    const float* __restrict__ x,
    const float* __restrict__ c,
    const float* __restrict__ psi,
    float* __restrict__ out)
{
    const int b = blockIdx.x * blockDim.x + threadIdx.x;  // B = 2^21 exact

    // ---- c[b,0:6] as 3x float2 (24 B/batch, 8B aligned) ----
    const float2* c2 = reinterpret_cast<const float2*>(c + (size_t)b * 6);
    const float2 ca = c2[0], cb = c2[1], cc = c2[2];
    const float cm[6] = {ca.x, ca.y, cb.x, cb.y, cc.x, cc.y};

    // ---- T = sum_m c[m] * psi[m]  (psi uniform -> scalarized s_loads) ----
    float T[9];
#pragma unroll
    for (int j = 0; j < 9; ++j) {
        float s = cm[0] * psi[0 * 9 + j];
#pragma unroll
        for (int m = 1; m < 6; ++m) s = fmaf(cm[m], psi[m * 9 + j], s);
        T[j] = s;
    }

    // ---- invariants of T, scaled to A = T/4:
    //      char poly: lam^3 = c2v lam^2 + c1v lam + c0v ----
    const float trT = T[0] + T[4] + T[8];
    const float m01 = fmaf(T[0], T[4], -T[1] * T[3]);
    const float m02 = fmaf(T[0], T[8], -T[2] * T[6]);
    const float m12 = fmaf(T[4], T[8], -T[5] * T[7]);
    const float msT = m01 + m02 + m12;
    const float M10 = fmaf(T[3], T[8], -T[5] * T[6]);
    const float M20 = fmaf(T[3], T[7], -T[4] * T[6]);
    const float detT = fmaf(T[0], m12, fmaf(-T[1], M10, T[2] * M20));
    const float c2v = trT * 0.25f;       // tr(A)
    const float c1v = msT * -0.0625f;    // -(sum principal minors of A)
    const float c0v = detT * 0.015625f;  // det(A)

    // lam^4 fold-back (shared by both squarings)
    const float d2 = fmaf(c2v, c2v, c1v);
    const float d1 = fmaf(c2v, c1v, c0v);
    const float d0 = c2v * c0v;

    // ---- order-8 Taylor, Horner in the quotient ring ----
    // h = 1/8!; for k=7..0: h = h*lam mod m + 1/k!
    const float tk[8] = {1.0f,            // 1/0!
                         1.0f,            // 1/1!
                         0.5f,            // 1/2!
                         1.6666667e-1f,   // 1/3!
                         4.1666667e-2f,   // 1/4!
                         8.3333333e-3f,   // 1/5!
                         1.3888889e-3f,   // 1/6!
                         1.9841270e-4f};  // 1/7!
    float b0 = 2.4801587e-5f, b1 = 0.0f, b2 = 0.0f;  // h = 1/8!
#pragma unroll
    for (int k = 7; k >= 0; --k) {
        const float n0 = fmaf(b2, c0v, tk[k]);  // tk const after unroll
        const float n1 = fmaf(b2, c1v, b0);
        const float n2 = fmaf(b2, c2v, b1);
        b0 = n0; b1 = n1; b2 = n2;
    }

    // ---- two squarings in coefficient space: b <- b^2 mod m ----
#pragma unroll
    for (int s2 = 0; s2 < 2; ++s2) {
        const float q0 = b0 * b0;
        const float q1 = 2.0f * (b0 * b1);
        const float q2 = fmaf(b1, b1, 2.0f * (b0 * b2));
        const float q3 = 2.0f * (b1 * b2);
        const float q4 = b2 * b2;
        b0 = fmaf(d0, q4, fmaf(c0v, q3, q0));
        b1 = fmaf(d1, q4, fmaf(c1v, q3, q1));
        b2 = fmaf(d2, q4, fmaf(c2v, q3, q2));
    }
    // exp(T) = b0 I + b1 A + b2 A^2,  A = T/4
    const float b1q = b1 * 0.25f;
    const float b2q = b2 * 0.0625f;

    // ---- y = b0 x + b1q (Tx) + b2q T(Tx) ----
    const float* xb = x + (size_t)b * 3;
    const float x0 = xb[0], x1 = xb[1], x2 = xb[2];
    const float w0 = fmaf(T[0], x0, fmaf(T[1], x1, T[2] * x2));
    const float w1 = fmaf(T[3], x0, fmaf(T[4], x1, T[5] * x2));
    const float w2 = fmaf(T[6], x0, fmaf(T[7], x1, T[8] * x2));
    const float v0 = fmaf(T[0], w0, fmaf(T[1], w1, T[2] * w2));
    const float v1 = fmaf(T[3], w0, fmaf(T[4], w1, T[5] * w2));
    const float v2 = fmaf(T[6], w0, fmaf(T[7], w1, T[8] * w2));

    float* ob = out + (size_t)b * 3;
    ob[0] = fmaf(b0, x0, fmaf(b1q, w0, b2q * v0));
    ob[1] = fmaf(b0, x1, fmaf(b1q, w1, b2q * v1));
    ob[2] = fmaf(b0, x2, fmaf(b1q, w2, b2q * v2));
}

extern "C" void kernel_launch(void* const* d_in, const int* in_sizes, int n_in,
                              void* d_out, int out_size, void* d_ws, size_t ws_size,
                              hipStream_t stream) {
    const float* x   = (const float*)d_in[0];  // [B,3,1]
    const float* c   = (const float*)d_in[1];  // [B,6]
    const float* psi = (const float*)d_in[2];  // [6,3,3]
    float* out = (float*)d_out;                // [B,3,1]

    const int B = in_sizes[1] / 6;  // 2097152 = 2^21, divisible by 256
    const int block = 256;
    const int grid = B / block;
    expm_kernel<<<grid, block, 0, stream>>>(x, c, psi, out);
}